// Round 7
// baseline (275.456 us; speedup 1.0000x reference)
//
#include <hip/hip_runtime.h>
#include <stdint.h>

#define NE 4096
#define FD 512
#define NCELLS 39
#define NPAIRS 8192

typedef __attribute__((ext_vector_type(8))) short short8;
typedef __attribute__((ext_vector_type(8))) unsigned short ushort8;
typedef __attribute__((ext_vector_type(4))) float f32x4;
typedef __attribute__((ext_vector_type(4))) unsigned int uint4v;

__device__ __forceinline__ unsigned short f2bf(float f) {
  union { float f; uint32_t u; } v; v.f = f;
  uint32_t u = v.u;
  return (unsigned short)((u + 0x7fffu + ((u >> 16) & 1u)) >> 16);  // RNE
}
__device__ __forceinline__ float bf2f(unsigned short b) {
  return __uint_as_float(((uint32_t)b) << 16);
}

__device__ __forceinline__ void async16(const void* g, void* l) {
  __builtin_amdgcn_global_load_lds((const __attribute__((address_space(1))) void*)g,
                                   (__attribute__((address_space(3))) void*)l, 16, 0, 0);
}

// ---- kernel 1: embedding fp32 -> bf16 ----
__global__ __launch_bounds__(256) void conv_e(const float* __restrict__ E,
                                              unsigned short* __restrict__ Ebf) {
  const int i = blockIdx.x * 256 + threadIdx.x;
  const float4 v = ((const float4*)E)[i];
  ushort4 o;
  o.x = f2bf(v.x); o.y = f2bf(v.y); o.z = f2bf(v.z); o.w = f2bf(v.w);
  ((ushort4*)Ebf)[i] = o;
}

// ---- kernel 2: Wt[ci][k][n] = wl[c,n] * wl[c,k] * W[n,k], bf16, transposed ----
__global__ __launch_bounds__(256) void prep_w(const float* __restrict__ W,
                                              const float* __restrict__ wl,
                                              unsigned short* __restrict__ Wt,
                                              int c0) {
  __shared__ float tile[32][33];
  const int ci = blockIdx.z;
  const int tn = blockIdx.x * 32, tk = blockIdx.y * 32;
  const int tx = threadIdx.x & 31, ty = threadIdx.x >> 5;
  const float* wlr = wl + (size_t)(c0 + ci) * FD;
#pragma unroll
  for (int i = 0; i < 4; i++) {
    int n = tn + ty + i * 8;
    tile[ty + i * 8][tx] = W[(size_t)n * FD + tk + tx] * wlr[n];
  }
  __syncthreads();
  unsigned short* dst = Wt + (size_t)ci * FD * FD;
#pragma unroll
  for (int i = 0; i < 4; i++) {
    int kout = tk + ty + i * 8;
    dst[(size_t)kout * FD + tn + tx] = f2bf(tile[tx][ty + i * 8] * wlr[kout]);
  }
}

// ---- kernel 3: bucket pairs by (cell, i0 >> 6), per cell ----
// word = p | (i1 << 13) | ((i0 & 63) << 25)   [13 + 12 + 6 = 31 bits]
__global__ __launch_bounds__(256) void bucket_k(const int* __restrict__ index,
                                                uint32_t* __restrict__ buckets,
                                                int* __restrict__ offs) {
  __shared__ int hist[64];
  __shared__ int base[64];
  __shared__ int cur[64];
  const int ci = blockIdx.x;
  const int t = threadIdx.x;
  if (t < 64) hist[t] = 0;
  __syncthreads();
  const int2* idx = (const int2*)index + (size_t)ci * NPAIRS;
  for (int j = t; j < NPAIRS; j += 256) {
    int2 id = idx[j];
    atomicAdd(&hist[id.x >> 6], 1);
  }
  __syncthreads();
  if (t == 0) {
    int s = 0;
    for (int b = 0; b < 64; b++) { base[b] = s; cur[b] = s; s += hist[b]; }
  }
  __syncthreads();
  if (t < 64) offs[ci * 64 + t] = base[t];
  for (int j = t; j < NPAIRS; j += 256) {
    int2 id = idx[j];
    int pos = atomicAdd(&cur[id.x >> 6], 1);
    buckets[(size_t)ci * NPAIRS + pos] =
        (uint32_t)j | ((uint32_t)id.y << 13) | ((uint32_t)(id.x & 63) << 25);
  }
}

// ---- kernel 4: U[ci][e][k] = sum_n Ebf[e,n] * Wt[ci][k][n]  (bf16 out) ----
// m97-style: 128x128 tile, BK=32, 4 waves (2x2), each wave 4x4 MFMA 16x16x32 tiles.
__global__ __launch_bounds__(256) void gemm_k(const unsigned short* __restrict__ Ebf,
                                              const unsigned short* __restrict__ Wt,
                                              unsigned short* __restrict__ U) {
  __shared__ unsigned short As[128 * 32];
  __shared__ unsigned short Bs[128 * 32];
  const int t = threadIdx.x;
  const int ci = blockIdx.z;
  const unsigned short* Ag = Ebf + (size_t)blockIdx.x * 128 * FD;
  const unsigned short* Bg = Wt + (size_t)ci * FD * FD + (size_t)blockIdx.y * 128 * FD;

  f32x4 acc[4][4];
#pragma unroll
  for (int i = 0; i < 4; i++)
#pragma unroll
    for (int j = 0; j < 4; j++) acc[i][j] = (f32x4){0.f, 0.f, 0.f, 0.f};

  const int wave = t >> 6, lane = t & 63;
  const int wm = (wave & 1) * 64, wn = (wave >> 1) * 64;
  const int lr = lane & 15, lq = lane >> 4;
  const int idx0 = t, idx1 = 256 + t;
  const int r0 = idx0 >> 2, cb0 = (idx0 & 3) * 8;
  const int r1 = idx1 >> 2, cb1 = (idx1 & 3) * 8;

  for (int k0 = 0; k0 < FD; k0 += 32) {
    async16(Ag + (size_t)r0 * FD + k0 + cb0, &As[idx0 * 8]);
    async16(Ag + (size_t)r1 * FD + k0 + cb1, &As[idx1 * 8]);
    async16(Bg + (size_t)r0 * FD + k0 + cb0, &Bs[idx0 * 8]);
    async16(Bg + (size_t)r1 * FD + k0 + cb1, &Bs[idx1 * 8]);
    __syncthreads();
    short8 af[4], bq[4];
#pragma unroll
    for (int mi = 0; mi < 4; mi++) af[mi] = *(const short8*)&As[(wm + mi * 16 + lr) * 32 + lq * 8];
#pragma unroll
    for (int ni = 0; ni < 4; ni++) bq[ni] = *(const short8*)&Bs[(wn + ni * 16 + lr) * 32 + lq * 8];
#pragma unroll
    for (int mi = 0; mi < 4; mi++)
#pragma unroll
      for (int ni = 0; ni < 4; ni++)
        acc[mi][ni] = __builtin_amdgcn_mfma_f32_16x16x32_bf16(af[mi], bq[ni], acc[mi][ni], 0, 0, 0);
    __syncthreads();
  }

  // epilogue: store bf16.  C/D: col=lane&15, row=(lane>>4)*4+reg
  unsigned short* Up = U + (size_t)ci * NE * FD;
#pragma unroll
  for (int mi = 0; mi < 4; mi++) {
    int mbase = blockIdx.x * 128 + wm + mi * 16 + lq * 4;
#pragma unroll
    for (int ni = 0; ni < 4; ni++) {
      int n = blockIdx.y * 128 + wn + ni * 16 + lr;
#pragma unroll
      for (int r = 0; r < 4; r++) {
        Up[(size_t)(mbase + r) * FD + n] = f2bf(acc[mi][ni][r]);
      }
    }
  }
}

// ---- kernel 5: bucketed dot. Block = (64-entity i0-window, cell). ----
// Stage the window's 64 U-rows (64KB) into LDS via coalesced global_load_lds,
// then per pair: gather E[i1] row (1KB, 64 lanes x 16B), dot vs LDS U-row.
// Full-K dots -> plain stores, no atomics.
__global__ __launch_bounds__(256) void dot_b(const unsigned short* __restrict__ U,
                                             const unsigned short* __restrict__ Ebf,
                                             const uint32_t* __restrict__ buckets,
                                             const int* __restrict__ offs,
                                             float* __restrict__ out,
                                             int c0) {
  __shared__ __align__(16) unsigned short Ul[64 * FD];  // 65536 B
  const int ci = blockIdx.y, bx = blockIdx.x;
  const int t = threadIdx.x;
  const int wave = t >> 6, lane = t & 63;

  const unsigned short* Uw = U + ((size_t)ci * NE + (size_t)bx * 64) * FD;
#pragma unroll
  for (int pass = 0; pass < 16; pass++)
    async16(Uw + pass * 2048 + t * 8, &Ul[pass * 2048 + t * 8]);
  __syncthreads();

  const int cg = c0 + ci;
  const int off0 = offs[cg * 64 + bx];
  const int off1 = (bx == 63) ? NPAIRS : offs[cg * 64 + bx + 1];
  const uint32_t* bk = buckets + (size_t)cg * NPAIRS;
  float* op = out + (size_t)cg * NPAIRS;

  for (int j = off0 + wave * 8; j < off1; j += 32) {
    const int m = off1 - j;  // >= 1
    uint32_t w[8];
#pragma unroll
    for (int b = 0; b < 8; b++) w[b] = bk[j + (b < m ? b : 0)];
    uint4v ev[8];
#pragma unroll
    for (int b = 0; b < 8; b++)
      ev[b] = *(const uint4v*)(Ebf + (size_t)((w[b] >> 13) & 0xFFF) * FD + lane * 8);
    ushort8 uu[8];
#pragma unroll
    for (int b = 0; b < 8; b++)
      uu[b] = *(const ushort8*)&Ul[(w[b] >> 25) * FD + lane * 8];
#pragma unroll
    for (int b = 0; b < 8; b++) {
      const ushort8 e = *(const ushort8*)&ev[b];
      float s = 0.f;
#pragma unroll
      for (int q = 0; q < 8; q++) s += bf2f(uu[b][q]) * bf2f(e[q]);
      s += __shfl_xor(s, 1, 64);
      s += __shfl_xor(s, 2, 64);
      s += __shfl_xor(s, 4, 64);
      s += __shfl_xor(s, 8, 64);
      s += __shfl_xor(s, 16, 64);
      s += __shfl_xor(s, 32, 64);
      if (lane == 0 && b < m) op[w[b] & 0x1FFF] = s;
    }
  }
}

// ---- fallback (tiny workspace): direct fp32, slow but correct ----
__global__ __launch_bounds__(256) void naive_k(const float* __restrict__ emb,
                                               const int* __restrict__ index,
                                               const float* __restrict__ W,
                                               const float* __restrict__ wl,
                                               float* __restrict__ out) {
  __shared__ float bs[FD];
  __shared__ float red[256];
  const int c = blockIdx.y, p = blockIdx.x;
  const int i0 = index[((size_t)c * NPAIRS + p) * 2];
  const int i1 = index[((size_t)c * NPAIRS + p) * 2 + 1];
  const float* wlc = wl + (size_t)c * FD;
  for (int k = threadIdx.x; k < FD; k += 256) bs[k] = emb[(size_t)i1 * FD + k] * wlc[k];
  __syncthreads();
  float s = 0.f;
  for (int n = threadIdx.x; n < FD; n += 256) {
    const float* wr = W + (size_t)n * FD;
    float tacc = 0.f;
    for (int k = 0; k < FD; k++) tacc += wr[k] * bs[k];
    s += tacc * emb[(size_t)i0 * FD + n] * wlc[n];
  }
  red[threadIdx.x] = s;
  __syncthreads();
  for (int st = 128; st > 0; st >>= 1) {
    if (threadIdx.x < st) red[threadIdx.x] += red[threadIdx.x + st];
    __syncthreads();
  }
  if (threadIdx.x == 0) out[(size_t)c * NPAIRS + p] = red[0];
}

extern "C" void kernel_launch(void* const* d_in, const int* in_sizes, int n_in,
                              void* d_out, int out_size, void* d_ws, size_t ws_size,
                              hipStream_t stream) {
  const float* emb = (const float*)d_in[0];
  const int* index = (const int*)d_in[1];
  const float* Wg = (const float*)d_in[2];
  const float* wl = (const float*)d_in[3];
  float* out = (float*)d_out;

  const size_t ebytes = (size_t)NE * FD * 2;          // 4 MiB bf16 embedding
  const size_t bbytes = (size_t)NCELLS * NPAIRS * 4;  // 1.25 MiB buckets
  const size_t obytes = (size_t)NCELLS * 64 * 4;      // 10 KiB offs
  const size_t wtcell = (size_t)FD * FD * 2;          // 0.5 MiB per-cell Wt
  const size_t ucell = (size_t)NE * FD * 2;           // 4 MiB per-cell U
  const size_t fixed = ebytes + bbytes + obytes;
  size_t avail = ws_size > fixed ? ws_size - fixed : 0;
  int G = (int)(avail / (wtcell + ucell));
  if (G > NCELLS) G = NCELLS;

  if (G < 1) {
    naive_k<<<dim3(NPAIRS, NCELLS), 256, 0, stream>>>(emb, index, Wg, wl, out);
    return;
  }

  unsigned short* Ebf = (unsigned short*)d_ws;
  uint32_t* buckets = (uint32_t*)((char*)d_ws + ebytes);
  int* offs = (int*)((char*)d_ws + ebytes + bbytes);
  unsigned short* Wt = (unsigned short*)((char*)d_ws + fixed);
  unsigned short* U = (unsigned short*)((char*)d_ws + fixed + (size_t)G * wtcell);

  conv_e<<<dim3((NE * FD / 4) / 256), 256, 0, stream>>>(emb, Ebf);
  bucket_k<<<dim3(NCELLS), 256, 0, stream>>>(index, buckets, offs);
  for (int c0 = 0; c0 < NCELLS; c0 += G) {
    int g = (NCELLS - c0 < G) ? (NCELLS - c0) : G;
    prep_w<<<dim3(FD / 32, FD / 32, g), 256, 0, stream>>>(Wg, wl, Wt, c0);
    gemm_k<<<dim3(NE / 128, FD / 128, g), 256, 0, stream>>>(Ebf, Wt, U);
    dot_b<<<dim3(64, g), 256, 0, stream>>>(U, Ebf, buckets, offs, out, c0);
  }
}

// Round 8
// 263.430 us; speedup vs baseline: 1.0457x; 1.0457x over previous
//
#include <hip/hip_runtime.h>
#include <stdint.h>

#define NE 4096
#define FD 512
#define NCELLS 39
#define NPAIRS 8192

typedef __attribute__((ext_vector_type(8))) short short8;
typedef __attribute__((ext_vector_type(8))) unsigned short ushort8;
typedef __attribute__((ext_vector_type(4))) float f32x4;
typedef __attribute__((ext_vector_type(4))) unsigned int uint4v;

__device__ __forceinline__ unsigned short f2bf(float f) {
  union { float f; uint32_t u; } v; v.f = f;
  uint32_t u = v.u;
  return (unsigned short)((u + 0x7fffu + ((u >> 16) & 1u)) >> 16);  // RNE
}
__device__ __forceinline__ float bf2f(unsigned short b) {
  return __uint_as_float(((uint32_t)b) << 16);
}

__device__ __forceinline__ void async16(const void* g, void* l) {
  __builtin_amdgcn_global_load_lds((const __attribute__((address_space(1))) void*)g,
                                   (__attribute__((address_space(3))) void*)l, 16, 0, 0);
}

// ---- kernel 1: embedding fp32 -> bf16 ----
__global__ __launch_bounds__(256) void conv_e(const float* __restrict__ E,
                                              unsigned short* __restrict__ Ebf) {
  const int i = blockIdx.x * 256 + threadIdx.x;
  const float4 v = ((const float4*)E)[i];
  ushort4 o;
  o.x = f2bf(v.x); o.y = f2bf(v.y); o.z = f2bf(v.z); o.w = f2bf(v.w);
  ((ushort4*)Ebf)[i] = o;
}

// ---- kernel 2: Wt[ci][k][n] = wl[c,n] * wl[c,k] * W[n,k], bf16, transposed ----
__global__ __launch_bounds__(256) void prep_w(const float* __restrict__ W,
                                              const float* __restrict__ wl,
                                              unsigned short* __restrict__ Wt,
                                              int c0) {
  __shared__ float tile[32][33];
  const int ci = blockIdx.z;
  const int tn = blockIdx.x * 32, tk = blockIdx.y * 32;
  const int tx = threadIdx.x & 31, ty = threadIdx.x >> 5;
  const float* wlr = wl + (size_t)(c0 + ci) * FD;
#pragma unroll
  for (int i = 0; i < 4; i++) {
    int n = tn + ty + i * 8;
    tile[ty + i * 8][tx] = W[(size_t)n * FD + tk + tx] * wlr[n];
  }
  __syncthreads();
  unsigned short* dst = Wt + (size_t)ci * FD * FD;
#pragma unroll
  for (int i = 0; i < 4; i++) {
    int kout = tk + ty + i * 8;
    dst[(size_t)kout * FD + tn + tx] = f2bf(tile[tx][ty + i * 8] * wlr[kout]);
  }
}

// ---- kernel 3: sort pair descriptors by i0-window (64 entities), per cell ----
// dsc.x = p | (i1 << 13), dsc.y = i0. Sorted order makes the dot phase walk U
// sequentially (64KB windows) instead of randomly over 160MB.
__global__ __launch_bounds__(256) void bucket_k(const int* __restrict__ index,
                                                uint2* __restrict__ dsc) {
  __shared__ int hist[64];
  __shared__ int cur[64];
  const int ci = blockIdx.x;
  const int t = threadIdx.x;
  if (t < 64) hist[t] = 0;
  __syncthreads();
  const int2* idx = (const int2*)index + (size_t)ci * NPAIRS;
  for (int j = t; j < NPAIRS; j += 256) {
    int2 id = idx[j];
    atomicAdd(&hist[id.x >> 6], 1);
  }
  __syncthreads();
  if (t == 0) {
    int s = 0;
    for (int b = 0; b < 64; b++) { cur[b] = s; s += hist[b]; }
  }
  __syncthreads();
  uint2* dc = dsc + (size_t)ci * NPAIRS;
  for (int j = t; j < NPAIRS; j += 256) {
    int2 id = idx[j];
    int pos = atomicAdd(&cur[id.x >> 6], 1);
    dc[pos] = make_uint2((uint32_t)j | ((uint32_t)id.y << 13), (uint32_t)id.x);
  }
}

// ---- kernel 4: U[ci][e][k] = sum_n Ebf[e,n] * Wt[ci][k][n]  (bf16 out) ----
// m97-style: 128x128 tile, BK=32, 4 waves (2x2), each wave 4x4 MFMA 16x16x32 tiles.
__global__ __launch_bounds__(256) void gemm_k(const unsigned short* __restrict__ Ebf,
                                              const unsigned short* __restrict__ Wt,
                                              unsigned short* __restrict__ U) {
  __shared__ unsigned short As[128 * 32];
  __shared__ unsigned short Bs[128 * 32];
  const int t = threadIdx.x;
  const int ci = blockIdx.z;
  const unsigned short* Ag = Ebf + (size_t)blockIdx.x * 128 * FD;
  const unsigned short* Bg = Wt + (size_t)ci * FD * FD + (size_t)blockIdx.y * 128 * FD;

  f32x4 acc[4][4];
#pragma unroll
  for (int i = 0; i < 4; i++)
#pragma unroll
    for (int j = 0; j < 4; j++) acc[i][j] = (f32x4){0.f, 0.f, 0.f, 0.f};

  const int wave = t >> 6, lane = t & 63;
  const int wm = (wave & 1) * 64, wn = (wave >> 1) * 64;
  const int lr = lane & 15, lq = lane >> 4;
  const int idx0 = t, idx1 = 256 + t;
  const int r0 = idx0 >> 2, cb0 = (idx0 & 3) * 8;
  const int r1 = idx1 >> 2, cb1 = (idx1 & 3) * 8;

  for (int k0 = 0; k0 < FD; k0 += 32) {
    async16(Ag + (size_t)r0 * FD + k0 + cb0, &As[idx0 * 8]);
    async16(Ag + (size_t)r1 * FD + k0 + cb1, &As[idx1 * 8]);
    async16(Bg + (size_t)r0 * FD + k0 + cb0, &Bs[idx0 * 8]);
    async16(Bg + (size_t)r1 * FD + k0 + cb1, &Bs[idx1 * 8]);
    __syncthreads();
    short8 af[4], bq[4];
#pragma unroll
    for (int mi = 0; mi < 4; mi++) af[mi] = *(const short8*)&As[(wm + mi * 16 + lr) * 32 + lq * 8];
#pragma unroll
    for (int ni = 0; ni < 4; ni++) bq[ni] = *(const short8*)&Bs[(wn + ni * 16 + lr) * 32 + lq * 8];
#pragma unroll
    for (int mi = 0; mi < 4; mi++)
#pragma unroll
      for (int ni = 0; ni < 4; ni++)
        acc[mi][ni] = __builtin_amdgcn_mfma_f32_16x16x32_bf16(af[mi], bq[ni], acc[mi][ni], 0, 0, 0);
    __syncthreads();
  }

  // epilogue: store bf16.  C/D: col=lane&15, row=(lane>>4)*4+reg
  unsigned short* Up = U + (size_t)ci * NE * FD;
#pragma unroll
  for (int mi = 0; mi < 4; mi++) {
    int mbase = blockIdx.x * 128 + wm + mi * 16 + lq * 4;
#pragma unroll
    for (int ni = 0; ni < 4; ni++) {
      int n = blockIdx.y * 128 + wn + ni * 16 + lr;
#pragma unroll
      for (int r = 0; r < 4; r++) {
        Up[(size_t)(mbase + r) * FD + n] = f2bf(acc[mi][ni][r]);
      }
    }
  }
}

// ---- kernel 5: out[c,p] = sum_k U[ci,i0,k] * Ebf[i1,k], i0-sorted order ----
// 64 lanes per pair, batches of 8 (16 loads in flight). U nontemporal (sequential
// read-once stream; protect L2 for the E table). E plain (4MB table, L2-hot).
__global__ __launch_bounds__(256) void dot_s(const unsigned short* __restrict__ U,
                                             const unsigned short* __restrict__ Ebf,
                                             const uint2* __restrict__ dsc,
                                             float* __restrict__ out,
                                             int c0) {
  const int ci = blockIdx.y;
  const int cg = c0 + ci;
  const int wave = threadIdx.x >> 6, lane = threadIdx.x & 63;
  const unsigned short* Uc = U + (size_t)ci * NE * FD;
  const uint2* dc = dsc + (size_t)cg * NPAIRS;
  float* op = out + (size_t)cg * NPAIRS;
  const int jbase = blockIdx.x * 128 + wave * 32;

  for (int batch = 0; batch < 4; batch++) {
    const int jb = jbase + batch * 8;
    uint2 d[8];
#pragma unroll
    for (int b = 0; b < 8; b++) d[b] = dc[jb + b];
    uint4v uv[8], ev[8];
#pragma unroll
    for (int b = 0; b < 8; b++) {
      uv[b] = __builtin_nontemporal_load((const uint4v*)(Uc + (size_t)d[b].y * FD + lane * 8));
      ev[b] = *(const uint4v*)(Ebf + (size_t)((d[b].x >> 13) & 0xFFF) * FD + lane * 8);
    }
#pragma unroll
    for (int b = 0; b < 8; b++) {
      const ushort8 u = *(const ushort8*)&uv[b];
      const ushort8 e = *(const ushort8*)&ev[b];
      float s = 0.f;
#pragma unroll
      for (int q = 0; q < 8; q++) s += bf2f(u[q]) * bf2f(e[q]);
      s += __shfl_xor(s, 1, 64);
      s += __shfl_xor(s, 2, 64);
      s += __shfl_xor(s, 4, 64);
      s += __shfl_xor(s, 8, 64);
      s += __shfl_xor(s, 16, 64);
      s += __shfl_xor(s, 32, 64);
      if (lane == b) op[d[b].x & 0x1FFF] = s;
    }
  }
}

// ---- fallback (tiny workspace): direct fp32, slow but correct ----
__global__ __launch_bounds__(256) void naive_k(const float* __restrict__ emb,
                                               const int* __restrict__ index,
                                               const float* __restrict__ W,
                                               const float* __restrict__ wl,
                                               float* __restrict__ out) {
  __shared__ float bs[FD];
  __shared__ float red[256];
  const int c = blockIdx.y, p = blockIdx.x;
  const int i0 = index[((size_t)c * NPAIRS + p) * 2];
  const int i1 = index[((size_t)c * NPAIRS + p) * 2 + 1];
  const float* wlc = wl + (size_t)c * FD;
  for (int k = threadIdx.x; k < FD; k += 256) bs[k] = emb[(size_t)i1 * FD + k] * wlc[k];
  __syncthreads();
  float s = 0.f;
  for (int n = threadIdx.x; n < FD; n += 256) {
    const float* wr = W + (size_t)n * FD;
    float tacc = 0.f;
    for (int k = 0; k < FD; k++) tacc += wr[k] * bs[k];
    s += tacc * emb[(size_t)i0 * FD + n] * wlc[n];
  }
  red[threadIdx.x] = s;
  __syncthreads();
  for (int st = 128; st > 0; st >>= 1) {
    if (threadIdx.x < st) red[threadIdx.x] += red[threadIdx.x + st];
    __syncthreads();
  }
  if (threadIdx.x == 0) out[(size_t)c * NPAIRS + p] = red[0];
}

extern "C" void kernel_launch(void* const* d_in, const int* in_sizes, int n_in,
                              void* d_out, int out_size, void* d_ws, size_t ws_size,
                              hipStream_t stream) {
  const float* emb = (const float*)d_in[0];
  const int* index = (const int*)d_in[1];
  const float* Wg = (const float*)d_in[2];
  const float* wl = (const float*)d_in[3];
  float* out = (float*)d_out;

  const size_t ebytes = (size_t)NE * FD * 2;          // 4 MiB bf16 embedding
  const size_t dbytes = (size_t)NCELLS * NPAIRS * 8;  // 2.44 MiB descriptors
  const size_t wtcell = (size_t)FD * FD * 2;          // 0.5 MiB per-cell Wt
  const size_t ucell = (size_t)NE * FD * 2;           // 4 MiB per-cell U
  const size_t fixed = ebytes + dbytes;
  size_t avail = ws_size > fixed ? ws_size - fixed : 0;
  int G = (int)(avail / (wtcell + ucell));
  if (G > NCELLS) G = NCELLS;

  if (G < 1) {
    naive_k<<<dim3(NPAIRS, NCELLS), 256, 0, stream>>>(emb, index, Wg, wl, out);
    return;
  }

  unsigned short* Ebf = (unsigned short*)d_ws;
  uint2* dsc = (uint2*)((char*)d_ws + ebytes);
  unsigned short* Wt = (unsigned short*)((char*)d_ws + fixed);
  unsigned short* U = (unsigned short*)((char*)d_ws + fixed + (size_t)G * wtcell);

  conv_e<<<dim3((NE * FD / 4) / 256), 256, 0, stream>>>(emb, Ebf);
  bucket_k<<<dim3(NCELLS), 256, 0, stream>>>(index, dsc);
  for (int c0 = 0; c0 < NCELLS; c0 += G) {
    int g = (NCELLS - c0 < G) ? (NCELLS - c0) : G;
    prep_w<<<dim3(FD / 32, FD / 32, g), 256, 0, stream>>>(Wg, wl, Wt, c0);
    gemm_k<<<dim3(NE / 128, FD / 128, g), 256, 0, stream>>>(Ebf, Wt, U);
    dot_s<<<dim3(NPAIRS / 128, g), 256, 0, stream>>>(U, Ebf, dsc, out, c0);
  }
}

// Round 9
// 246.562 us; speedup vs baseline: 1.1172x; 1.0684x over previous
//
#include <hip/hip_runtime.h>
#include <stdint.h>

#define NE 4096
#define FD 512
#define NCELLS 39
#define NPAIRS 8192

typedef __attribute__((ext_vector_type(8))) short short8;
typedef __attribute__((ext_vector_type(8))) unsigned short ushort8;
typedef __attribute__((ext_vector_type(4))) float f32x4;

__device__ __forceinline__ unsigned short f2bf(float f) {
  union { float f; uint32_t u; } v; v.f = f;
  uint32_t u = v.u;
  return (unsigned short)((u + 0x7fffu + ((u >> 16) & 1u)) >> 16);  // RNE
}

__device__ __forceinline__ void async16(const void* g, void* l) {
  __builtin_amdgcn_global_load_lds((const __attribute__((address_space(1))) void*)g,
                                   (__attribute__((address_space(3))) void*)l, 16, 0, 0);
}

// ---- kernel 1: embedding fp32 -> bf16 ----
__global__ __launch_bounds__(256) void conv_e(const float* __restrict__ E,
                                              unsigned short* __restrict__ Ebf) {
  const int i = blockIdx.x * 256 + threadIdx.x;
  const float4 v = ((const float4*)E)[i];
  ushort4 o;
  o.x = f2bf(v.x); o.y = f2bf(v.y); o.z = f2bf(v.z); o.w = f2bf(v.w);
  ((ushort4*)Ebf)[i] = o;
}

// ---- kernel 2: Wt[ci][k][n] = wl[c,n] * wl[c,k] * W[n,k], bf16, transposed ----
// Both wl factors folded so the gemm accumulator IS U directly.
__global__ __launch_bounds__(256) void prep_w(const float* __restrict__ W,
                                              const float* __restrict__ wl,
                                              unsigned short* __restrict__ Wt,
                                              int c0) {
  __shared__ float tile[32][33];
  const int ci = blockIdx.z;
  const int tn = blockIdx.x * 32, tk = blockIdx.y * 32;
  const int tx = threadIdx.x & 31, ty = threadIdx.x >> 5;
  const float* wlr = wl + (size_t)(c0 + ci) * FD;
#pragma unroll
  for (int i = 0; i < 4; i++) {
    int n = tn + ty + i * 8;
    tile[ty + i * 8][tx] = W[(size_t)n * FD + tk + tx] * wlr[n];
  }
  __syncthreads();
  unsigned short* dst = Wt + (size_t)ci * FD * FD;
#pragma unroll
  for (int i = 0; i < 4; i++) {
    int kout = tk + ty + i * 8;
    dst[(size_t)kout * FD + tn + tx] = f2bf(tile[tx][ty + i * 8] * wlr[kout]);
  }
}

// ---- kernel 3: U[ci][e][k] = sum_n Ebf[e,n] * Wt[ci][k][n]  (bf16 out) ----
// m97-style: 128x128 tile, BK=32, 4 waves (2x2), each wave 4x4 MFMA 16x16x32 tiles.
__global__ __launch_bounds__(256) void gemm_k(const unsigned short* __restrict__ Ebf,
                                              const unsigned short* __restrict__ Wt,
                                              unsigned short* __restrict__ U) {
  __shared__ unsigned short As[128 * 32];
  __shared__ unsigned short Bs[128 * 32];
  const int t = threadIdx.x;
  const int ci = blockIdx.z;
  const unsigned short* Ag = Ebf + (size_t)blockIdx.x * 128 * FD;
  const unsigned short* Bg = Wt + (size_t)ci * FD * FD + (size_t)blockIdx.y * 128 * FD;

  f32x4 acc[4][4];
#pragma unroll
  for (int i = 0; i < 4; i++)
#pragma unroll
    for (int j = 0; j < 4; j++) acc[i][j] = (f32x4){0.f, 0.f, 0.f, 0.f};

  const int wave = t >> 6, lane = t & 63;
  const int wm = (wave & 1) * 64, wn = (wave >> 1) * 64;
  const int lr = lane & 15, lq = lane >> 4;
  const int idx0 = t, idx1 = 256 + t;
  const int r0 = idx0 >> 2, cb0 = (idx0 & 3) * 8;
  const int r1 = idx1 >> 2, cb1 = (idx1 & 3) * 8;

  for (int k0 = 0; k0 < FD; k0 += 32) {
    async16(Ag + (size_t)r0 * FD + k0 + cb0, &As[idx0 * 8]);
    async16(Ag + (size_t)r1 * FD + k0 + cb1, &As[idx1 * 8]);
    async16(Bg + (size_t)r0 * FD + k0 + cb0, &Bs[idx0 * 8]);
    async16(Bg + (size_t)r1 * FD + k0 + cb1, &Bs[idx1 * 8]);
    __syncthreads();
    short8 af[4], bq[4];
#pragma unroll
    for (int mi = 0; mi < 4; mi++) af[mi] = *(const short8*)&As[(wm + mi * 16 + lr) * 32 + lq * 8];
#pragma unroll
    for (int ni = 0; ni < 4; ni++) bq[ni] = *(const short8*)&Bs[(wn + ni * 16 + lr) * 32 + lq * 8];
#pragma unroll
    for (int mi = 0; mi < 4; mi++)
#pragma unroll
      for (int ni = 0; ni < 4; ni++)
        acc[mi][ni] = __builtin_amdgcn_mfma_f32_16x16x32_bf16(af[mi], bq[ni], acc[mi][ni], 0, 0, 0);
    __syncthreads();
  }

  // epilogue: store bf16.  C/D: col=lane&15, row=(lane>>4)*4+reg
  unsigned short* Up = U + (size_t)ci * NE * FD;
#pragma unroll
  for (int mi = 0; mi < 4; mi++) {
    int mbase = blockIdx.x * 128 + wm + mi * 16 + lq * 4;
#pragma unroll
    for (int ni = 0; ni < 4; ni++) {
      int n = blockIdx.y * 128 + wn + ni * 16 + lr;
#pragma unroll
      for (int r = 0; r < 4; r++) {
        Up[(size_t)(mbase + r) * FD + n] = f2bf(acc[mi][ni][r]);
      }
    }
  }
}

// ---- kernel 4: pair dots via MFMA diagonal ----
// Wave handles 16 pairs. A-frag rows = U[i0[m]], B-frag rows = Ebf[i1[n]];
// C = A·B^T accumulated over K=512 (16 MFMA steps); diagonal C[m][m] = out.
// A-frag layout (16x16x32): lane l holds row m=l&15, k = s*32 + (l>>4)*8 .. +8.
__global__ __launch_bounds__(256) void dot_m(const unsigned short* __restrict__ U,
                                             const unsigned short* __restrict__ Ebf,
                                             const int* __restrict__ index,
                                             float* __restrict__ out,
                                             int c0) {
  const int ci = blockIdx.y;
  const int cg = c0 + ci;
  const int wave = threadIdx.x >> 6, lane = threadIdx.x & 63;
  const int m = lane & 15, kg = lane >> 4;
  const size_t cp = (size_t)cg * NPAIRS;
  const int jb = (blockIdx.x * 4 + wave) * 16;

  const int2 id = ((const int2*)index)[cp + jb + m];
  const unsigned short* ar = U + (size_t)ci * NE * FD + (size_t)id.x * FD + kg * 8;
  const unsigned short* br = Ebf + (size_t)id.y * FD + kg * 8;

  f32x4 acc = (f32x4){0.f, 0.f, 0.f, 0.f};
#pragma unroll
  for (int s = 0; s < 16; s++) {
    const short8 a = *(const short8*)(ar + s * 32);
    const short8 b = *(const short8*)(br + s * 32);
    acc = __builtin_amdgcn_mfma_f32_16x16x32_bf16(a, b, acc, 0, 0, 0);
  }
  // diagonal: lane holds col=lane&15, rows (lane>>4)*4+r. Need row==col.
  const int r = m - kg * 4;
  if (r >= 0 && r < 4) out[cp + jb + m] = acc[r];
}

// ---- fallback (tiny workspace): direct fp32, slow but correct ----
__global__ __launch_bounds__(256) void naive_k(const float* __restrict__ emb,
                                               const int* __restrict__ index,
                                               const float* __restrict__ W,
                                               const float* __restrict__ wl,
                                               float* __restrict__ out) {
  __shared__ float bs[FD];
  __shared__ float red[256];
  const int c = blockIdx.y, p = blockIdx.x;
  const int i0 = index[((size_t)c * NPAIRS + p) * 2];
  const int i1 = index[((size_t)c * NPAIRS + p) * 2 + 1];
  const float* wlc = wl + (size_t)c * FD;
  for (int k = threadIdx.x; k < FD; k += 256) bs[k] = emb[(size_t)i1 * FD + k] * wlc[k];
  __syncthreads();
  float s = 0.f;
  for (int n = threadIdx.x; n < FD; n += 256) {
    const float* wr = W + (size_t)n * FD;
    float tacc = 0.f;
    for (int k = 0; k < FD; k++) tacc += wr[k] * bs[k];
    s += tacc * emb[(size_t)i0 * FD + n] * wlc[n];
  }
  red[threadIdx.x] = s;
  __syncthreads();
  for (int st = 128; st > 0; st >>= 1) {
    if (threadIdx.x < st) red[threadIdx.x] += red[threadIdx.x + st];
    __syncthreads();
  }
  if (threadIdx.x == 0) out[(size_t)c * NPAIRS + p] = red[0];
}

extern "C" void kernel_launch(void* const* d_in, const int* in_sizes, int n_in,
                              void* d_out, int out_size, void* d_ws, size_t ws_size,
                              hipStream_t stream) {
  const float* emb = (const float*)d_in[0];
  const int* index = (const int*)d_in[1];
  const float* Wg = (const float*)d_in[2];
  const float* wl = (const float*)d_in[3];
  float* out = (float*)d_out;

  const size_t ebytes = (size_t)NE * FD * 2;  // 4 MiB bf16 embedding
  const size_t wtcell = (size_t)FD * FD * 2;  // 0.5 MiB per-cell Wt
  const size_t ucell = (size_t)NE * FD * 2;   // 4 MiB per-cell U
  size_t avail = ws_size > ebytes ? ws_size - ebytes : 0;
  int G = (int)(avail / (wtcell + ucell));
  if (G > NCELLS) G = NCELLS;

  if (G < 1) {
    naive_k<<<dim3(NPAIRS, NCELLS), 256, 0, stream>>>(emb, index, Wg, wl, out);
    return;
  }

  unsigned short* Ebf = (unsigned short*)d_ws;
  unsigned short* Wt = (unsigned short*)((char*)d_ws + ebytes);
  unsigned short* U = (unsigned short*)((char*)d_ws + ebytes + (size_t)G * wtcell);

  conv_e<<<dim3((NE * FD / 4) / 256), 256, 0, stream>>>(emb, Ebf);
  for (int c0 = 0; c0 < NCELLS; c0 += G) {
    int g = (NCELLS - c0 < G) ? (NCELLS - c0) : G;
    prep_w<<<dim3(FD / 32, FD / 32, g), 256, 0, stream>>>(Wg, wl, Wt, c0);
    gemm_k<<<dim3(NE / 128, FD / 128, g), 256, 0, stream>>>(Ebf, Wt, U);
    dot_m<<<dim3(NPAIRS / 64, g), 256, 0, stream>>>(U, Ebf, index, out, c0);
  }
}